// Round 10
// baseline (943.070 us; speedup 1.0000x reference)
//
#include <hip/hip_runtime.h>
#include <hip/hip_bf16.h>

#define Bn 4096
#define Tn 8
#define Hn 512

typedef __attribute__((ext_vector_type(8))) _Float16 half8v;
typedef __attribute__((ext_vector_type(4))) float f32x4;

__device__ __forceinline__ float sigm(float x) { return 0.5f * tanhf(0.5f * x) + 0.5f; }

__device__ __forceinline__ short f2h(float x) {
    _Float16 h = (_Float16)x;
    return *reinterpret_cast<short*>(&h);
}
__device__ __forceinline__ float h2f(short s) {
    _Float16 h = *reinterpret_cast<_Float16*>(&s);
    return (float)h;
}
// x ~= hi + lo*2^-12 ; lo pre-scaled by 2^12 so it stays fp16-normal
__device__ __forceinline__ void split2(float x, short& hi, short& lo) {
    hi = f2h(x);
    lo = f2h((x - h2f(hi)) * 4096.0f);
}

#define GLOAD16(g, l) __builtin_amdgcn_global_load_lds( \
    (const __attribute__((address_space(1))) unsigned int*)(g), \
    (__attribute__((address_space(3))) unsigned int*)(l), 16, 0, 0)

// ---------------- setup kernels ----------------

// Wcat rows remapped: j' = (h&15) | (gate<<4) | ((h>>4)<<6), source row = gate*512 + h.
__global__ __launch_bounds__(256) void k_prep(const float* __restrict__ Wih,
                                              const float* __restrict__ Whh,
                                              const float* __restrict__ bih,
                                              const float* __restrict__ bhh,
                                              short* __restrict__ WcatHi,
                                              short* __restrict__ WcatLo,
                                              float* __restrict__ bcat) {
    int tid = blockIdx.x * 256 + threadIdx.x;   // over 2048*1024
    int jp = tid >> 10, k = tid & 1023;
    int g = (jp >> 4) & 3;
    int h = (jp & 15) + ((jp >> 6) << 4);
    int j = g * 512 + h;                        // source row in [Wih|Whh]
    float v = (k < 512) ? Wih[j * 512 + k] : Whh[j * 512 + (k - 512)];
    short hi, lo; split2(v, hi, lo);
    WcatHi[tid] = hi; WcatLo[tid] = lo;
    if (k == 0) bcat[jp] = bih[j] + bhh[j];
}

__global__ __launch_bounds__(256) void k_split4(const float* __restrict__ x,
                                                short* __restrict__ hi,
                                                short* __restrict__ lo, int n4) {
    int i = blockIdx.x * 256 + threadIdx.x;
    if (i >= n4) return;
    float4 v = ((const float4*)x)[i];
    short h0, l0, h1, l1, h2, l2, h3, l3;
    split2(v.x, h0, l0); split2(v.y, h1, l1);
    split2(v.z, h2, l2); split2(v.w, h3, l3);
    ((short4*)hi)[i] = make_short4(h0, h1, h2, h3);
    ((short4*)lo)[i] = make_short4(l0, l1, l2, l3);
}

// inp0 = sum_t enc[b,t,h]*cw[t] + cb ; zero h-part of X0, zero C, zero mask
__global__ __launch_bounds__(256) void k_init(const float* __restrict__ enc,
                                              const float* __restrict__ cw,
                                              const float* __restrict__ cb,
                                              short* __restrict__ Xhi,
                                              short* __restrict__ Xlo,
                                              float* __restrict__ C,
                                              int* __restrict__ mask) {
    int tid = blockIdx.x * 256 + threadIdx.x;   // over B*H
    int b = tid >> 9, h = tid & 511;
    float s = cb[0];
    const float* e = enc + ((size_t)b << 12) + h;
#pragma unroll
    for (int t = 0; t < Tn; ++t) s = fmaf(e[t * Hn], cw[t], s);
    short hi, lo; split2(s, hi, lo);
    size_t xb = ((size_t)b << 10) + h;
    Xhi[xb] = hi; Xlo[xb] = lo;
    Xhi[xb + 512] = 0; Xlo[xb + 512] = 0;
    C[tid] = 0.0f;
    if (h == 0) mask[b] = 0;
}

// ---------------- split-fp16 MFMA GEMM, counted-vmcnt pipelined (T3+T4) --------------
// C[m,n] = sum_k (Ahi + Alo*2^-12)[m,k] * (Whi + Wlo*2^-12)[n,k] + bias[n]
// BM=128, BN=32*NW, BK=32; 4 waves as 2x2. Double-buffered LDS, triple-depth
// prefetch: STAGE(kt+2) issued while computing kt; steady-state waits are
// vmcnt(LOADS) (8 for NW=4, 6 for NW=2), NEVER 0 until the final iteration.
// Per K-step: vmcnt(N); barrier; ds_read; lgkmcnt(0); barrier; STAGE; MFMA.
// SWZ: bijective XCD-aware blockIdx remap (XCD = linear wgid % 8):
//   1: grid(16,32) -> 8x8 super-tile per XCD   (gates)
//   2: grid(4,256) -> 32 full rows per XCD     (W1E)
//   3: grid(8,32)  -> 8x4 super-tile per XCD   (W2h)
template <int NW, bool FUSE, int SWZ>
__global__ __launch_bounds__(256) void gemm_t(
    const short* __restrict__ Ahi, const short* __restrict__ Alo, int lda,
    const short* __restrict__ Whi, const short* __restrict__ Wlo,
    const float* __restrict__ bias, float* __restrict__ out,
    float* __restrict__ Cst, short* __restrict__ Xh, short* __restrict__ Xl,
    int N, int K) {
    constexpr int BN = 32 * NW;
    constexpr int BUFSH = (256 + 2 * BN) * 32;     // shorts per buffer
    __shared__ short sm[2 * BUFSH];

    int bx = blockIdx.x, by = blockIdx.y;
    if constexpr (SWZ == 1) {
        int w = bx + (by << 4), c = w & 7, k = w >> 3;
        by = ((c >> 1) << 3) | (k >> 3);
        bx = ((c & 1) << 3) | (k & 7);
    } else if constexpr (SWZ == 2) {
        int w = bx + (by << 2), c = w & 7, k = w >> 3;
        by = (c << 5) | (k >> 2);
        bx = k & 3;
    } else if constexpr (SWZ == 3) {
        int w = bx + (by << 3), c = w & 7, k = w >> 3;
        by = ((c >> 1) << 3) | (k >> 2);
        bx = ((c & 1) << 2) | (k & 3);
    }

    const int tid = threadIdx.x;
    const int lane = tid & 63;
    const int wv = tid >> 6;
    const int wm = wv >> 1, wn = wv & 1;
    const int lm = lane & 15, lk = lane >> 4;
    const int m0 = by * 128, n0 = bx * BN;

    const int sq = lane & 3;
    const int srow = wv * 16 + (lane >> 2);

    f32x4 acc[4][NW] = {};
    f32x4 acc2[4][NW] = {};

    float bb[NW];
#pragma unroll
    for (int j = 0; j < NW; ++j) bb[j] = bias[n0 + wn * (16 * NW) + j * 16 + lm];

    // stage tile kt into buffer buf: issues exactly (4 + BN/32) GLOAD16 per thread
    auto STAGE = [&](int buf, int kt) {
        short* base = sm + buf * BUFSH;
        int k0 = kt << 5;
#pragma unroll
        for (int half = 0; half < 2; ++half) {
            int r = half * 64 + srow;
            int qg = sq ^ ((r >> 1) & 3);
            size_t aoff = (size_t)(m0 + r) * lda + k0 + qg * 8;
            int lb = half * 2048 + wv * 512;
            GLOAD16(Ahi + aoff, base + lb);
            GLOAD16(Alo + aoff, base + 128 * 32 + lb);
        }
#pragma unroll
        for (int half = 0; half < BN / 64; ++half) {
            int r = half * 64 + srow;
            int qg = sq ^ ((r >> 1) & 3);
            size_t boff = (size_t)(n0 + r) * K + k0 + qg * 8;
            int lb = half * 2048 + wv * 512;
            GLOAD16(Whi + boff, base + 256 * 32 + lb);
            GLOAD16(Wlo + boff, base + (256 + BN) * 32 + lb);
        }
    };

    const int nkt = K >> 5;                        // >= 16 for all our shapes
    // drain bias loads so the counted vmcnt waits below are exact
    asm volatile("s_waitcnt vmcnt(0)" ::: "memory");
    __builtin_amdgcn_sched_barrier(0);
    STAGE(0, 0);
    STAGE(1, 1);

    for (int kt = 0; kt < nkt; ++kt) {
        const int cur = kt & 1;
        // wait for buf[cur]'s stage (oldest LOADS entries); newer stage keeps flying
        if (kt == nkt - 1) {
            asm volatile("s_waitcnt vmcnt(0)" ::: "memory");
        } else {
            if constexpr (NW == 4) asm volatile("s_waitcnt vmcnt(8)" ::: "memory");
            else                   asm volatile("s_waitcnt vmcnt(6)" ::: "memory");
        }
        __builtin_amdgcn_s_barrier();              // all waves' buf[cur] writes visible
        __builtin_amdgcn_sched_barrier(0);         // pin: no ds_read above this point

        short* smAhi = sm + cur * BUFSH;
        short* smAlo = smAhi + 128 * 32;
        short* smBhi = smAhi + 256 * 32;
        short* smBlo = smAhi + (256 + BN) * 32;

        half8v ahi[4], alo[4], bhi[NW], blo[NW];
#pragma unroll
        for (int i = 0; i < 4; ++i) {
            int ra = wm * 64 + i * 16 + lm;
            int offa = ra * 32 + (lk ^ ((ra >> 1) & 3)) * 8;
            ahi[i] = *(const half8v*)&smAhi[offa];
            alo[i] = *(const half8v*)&smAlo[offa];
        }
#pragma unroll
        for (int j = 0; j < NW; ++j) {
            int rb = wn * (16 * NW) + j * 16 + lm;
            int offb = rb * 32 + (lk ^ ((rb >> 1) & 3)) * 8;
            bhi[j] = *(const half8v*)&smBhi[offb];
            blo[j] = *(const half8v*)&smBlo[offb];
        }
        asm volatile("s_waitcnt lgkmcnt(0)" ::: "memory");  // my reads done
        __builtin_amdgcn_sched_barrier(0);
        __builtin_amdgcn_s_barrier();              // ALL waves' reads done -> safe to restage
        __builtin_amdgcn_sched_barrier(0);         // pin: STAGE stays below the barrier
        if (kt + 2 < nkt) STAGE(cur, kt + 2);      // refill buf[cur]; flies under 2 phases

        __builtin_amdgcn_s_setprio(1);
#pragma unroll
        for (int i = 0; i < 4; ++i)
#pragma unroll
            for (int j = 0; j < NW; ++j) {
                acc[i][j]  = __builtin_amdgcn_mfma_f32_16x16x32_f16(ahi[i], bhi[j], acc[i][j], 0, 0, 0);
                acc2[i][j] = __builtin_amdgcn_mfma_f32_16x16x32_f16(ahi[i], blo[j], acc2[i][j], 0, 0, 0);
                acc2[i][j] = __builtin_amdgcn_mfma_f32_16x16x32_f16(alo[i], bhi[j], acc2[i][j], 0, 0, 0);
            }
        __builtin_amdgcn_s_setprio(0);
    }

    const float ls = 1.0f / 4096.0f;

    if constexpr (FUSE) {
        // col = n0 + wn*64 + gate*16 + lm  ->  gate = j, h = lm + 16*(n0/64 + wn)
        const int h = lm + 16 * ((n0 >> 6) + wn);
#pragma unroll
        for (int i = 0; i < 4; ++i) {
#pragma unroll
            for (int r = 0; r < 4; ++r) {
                int brow = m0 + wm * 64 + i * 16 + lk * 4 + r;
                float gi = acc[i][0][r] + ls * acc2[i][0][r] + bb[0];
                float gf = acc[i][1][r] + ls * acc2[i][1][r] + bb[1];
                float gg = acc[i][2][r] + ls * acc2[i][2][r] + bb[2];
                float go = acc[i][3][r] + ls * acc2[i][3][r] + bb[3];
                size_t ch = ((size_t)brow << 9) + h;
                float c = sigm(gf) * Cst[ch] + sigm(gi) * tanhf(gg);
                float hn = sigm(go) * tanhf(c);
                Cst[ch] = c;
                short shi, slo; split2(hn, shi, slo);
                size_t xb = ((size_t)brow << 10) + 512 + h;
                Xh[xb] = shi; Xl[xb] = slo;
            }
        }
    } else {
        __syncthreads();                            // LDS reuse: all tile reads complete
        // LDS-transpose epilogue -> coalesced float4 stores
        constexpr int SW = 16 * NW + 4;
        float* tile = reinterpret_cast<float*>(sm) + wv * 16 * SW;
        constexpr int LPR = 4 * NW;
        const int rl = lane / LPR, cc = lane % LPR;
#pragma unroll
        for (int i = 0; i < 4; ++i) {
#pragma unroll
            for (int j = 0; j < NW; ++j)
#pragma unroll
                for (int r = 0; r < 4; ++r)
                    tile[(lk * 4 + r) * SW + j * 16 + lm] = acc[i][j][r] + ls * acc2[i][j][r] + bb[j];
            constexpr int RPS = 64 / LPR;
#pragma unroll
            for (int s = 0; s < 16 / RPS; ++s) {
                int row = s * RPS + rl;
                float4 v = *(float4*)&tile[row * SW + cc * 4];
                *(float4*)(out + (size_t)(m0 + wm * 64 + i * 16 + row) * N +
                           n0 + wn * (16 * NW) + cc * 4) = v;
            }
        }
    }
}

// ---------------- attention + argmax + mask + gather into X_next ----------------
// 4 waves; wave wv owns t = 2*wv and 2*wv+1 (full 512-dot per wave).
__global__ __launch_bounds__(256) void k_attn(const float* __restrict__ W1E,
                                              const float* __restrict__ W2h,
                                              const float* __restrict__ vw,
                                              const float* __restrict__ vbp,
                                              const float* __restrict__ inps,
                                              short* __restrict__ Xhi,
                                              short* __restrict__ Xlo,
                                              int* __restrict__ mask,
                                              float* __restrict__ probs,
                                              float* __restrict__ ptrs,
                                              int step) {
    const int b = blockIdx.x;
    const int tid = threadIdx.x;
    const int lane = tid & 63;
    const int wv = tid >> 6;
    __shared__ float sU[Tn];
    __shared__ int sptr;

    const float4* w2p = (const float4*)(W2h + (size_t)b * Hn + lane * 8);
    float4 w2a = w2p[0], w2b = w2p[1];
    const float4* vp = (const float4*)(vw + lane * 8);
    float4 va = vp[0], vb4 = vp[1];
    float vbias = vbp[0];

#pragma unroll
    for (int q = 0; q < 2; ++q) {
        int t = wv * 2 + q;
        const float4* w1 = (const float4*)(W1E + ((size_t)b << 12) + t * Hn + lane * 8);
        float4 u0 = w1[0], u1 = w1[1];
        float p = va.x * tanhf(u0.x + w2a.x) + va.y * tanhf(u0.y + w2a.y)
                + va.z * tanhf(u0.z + w2a.z) + va.w * tanhf(u0.w + w2a.w)
                + vb4.x * tanhf(u1.x + w2b.x) + vb4.y * tanhf(u1.y + w2b.y)
                + vb4.z * tanhf(u1.z + w2b.z) + vb4.w * tanhf(u1.w + w2b.w);
#pragma unroll
        for (int off = 32; off; off >>= 1) p += __shfl_down(p, off, 64);
        if (lane == 0) sU[t] = p + vbias;
    }
    __syncthreads();

    if (tid == 0) {
        int mk = mask[b];
        float best = -1e30f;
        int ptr = 0;
#pragma unroll
        for (int t = 0; t < Tn; ++t) {
            probs[(size_t)b * 64 + step * 8 + t] = sU[t];
            if (!((mk >> t) & 1) && sU[t] > best) { best = sU[t]; ptr = t; }
        }
        mask[b] = mk | (1 << ptr);
        ptrs[(size_t)b * 8 + step] = (float)ptr;
        sptr = ptr;
    }
    __syncthreads();
    const float2* src = (const float2*)(inps + ((size_t)b << 12) + (size_t)sptr * Hn);
    float2 v = src[tid];
    short h0, l0, h1, l1;
    split2(v.x, h0, l0); split2(v.y, h1, l1);
    size_t xb = ((size_t)b << 10) + tid * 2;
    *(short2*)&Xhi[xb] = make_short2(h0, h1);
    *(short2*)&Xlo[xb] = make_short2(l0, l1);
}

// ---------------- launch ----------------
extern "C" void kernel_launch(void* const* d_in, const int* in_sizes, int n_in,
                              void* d_out, int out_size, void* d_ws, size_t ws_size,
                              hipStream_t stream) {
    const float* inps  = (const float*)d_in[0];
    const float* enc   = (const float*)d_in[1];
    const float* convw = (const float*)d_in[2];
    const float* convb = (const float*)d_in[3];
    const float* Wih   = (const float*)d_in[4];
    const float* Whh   = (const float*)d_in[5];
    const float* bih   = (const float*)d_in[6];
    const float* bhh   = (const float*)d_in[7];
    const float* W1    = (const float*)d_in[8];
    const float* b1    = (const float*)d_in[9];
    const float* W2    = (const float*)d_in[10];
    const float* b2    = (const float*)d_in[11];
    const float* vw    = (const float*)d_in[12];
    const float* vb    = (const float*)d_in[13];

    float* out   = (float*)d_out;
    float* probs = out;                       // [B, 8, 8]
    float* ptrs  = out + (size_t)Bn * 64;     // [B, 8] as float

    char* wsb = (char*)d_ws;
    float* W1E    = (float*)wsb;                          // [0,64MB) fp32 [B*T,512]
    short* encHi  = (short*)(wsb + (64ull << 20));        // dead after W1E gemm
    short* encLo  = (short*)(wsb + (96ull << 20));        // dead after W1E gemm
    short* Xhi1   = (short*)(wsb + (64ull << 20));        // 8MB fp16 [B,1024]
    short* Xlo1   = (short*)(wsb + (72ull << 20));        // 8MB
    float* W2h    = (float*)(wsb + (96ull << 20));        // 8MB fp32 [B,512]
    float* C      = (float*)(wsb + (104ull << 20));       // 8MB fp32 [B,512]
    short* Xhi0   = (short*)(wsb + (112ull << 20));       // 8MB
    short* Xlo0   = (short*)(wsb + (120ull << 20));       // 8MB
    short* WcatHi = (short*)(wsb + (128ull << 20));       // 4MB [2048,1024]
    short* WcatLo = (short*)(wsb + (132ull << 20));       // 4MB
    short* W1hi   = (short*)(wsb + (136ull << 20));
    short* W1lo   = (short*)(wsb + (136ull << 20) + (512u << 10));
    short* W2hi   = (short*)(wsb + (137ull << 20));
    short* W2lo   = (short*)(wsb + (137ull << 20) + (512u << 10));
    float* bcat   = (float*)(wsb + (138ull << 20));
    int*   mask   = (int*)(wsb + (138ull << 20) + (16u << 10));

    k_prep<<<(2048 * 1024) / 256, 256, 0, stream>>>(Wih, Whh, bih, bhh, WcatHi, WcatLo, bcat);
    k_split4<<<(Bn * Tn * Hn / 4) / 256, 256, 0, stream>>>(enc, encHi, encLo, Bn * Tn * Hn / 4);
    k_split4<<<(Hn * Hn / 4) / 256, 256, 0, stream>>>(W1, W1hi, W1lo, Hn * Hn / 4);
    k_split4<<<(Hn * Hn / 4) / 256, 256, 0, stream>>>(W2, W2hi, W2lo, Hn * Hn / 4);

    // W1E = enc @ W1^T + b1   [B*T, 512], K=512
    gemm_t<4, false, 2><<<dim3(Hn / 128, (Bn * Tn) / 128), 256, 0, stream>>>(
        encHi, encLo, Hn, W1hi, W1lo, b1, W1E, nullptr, nullptr, nullptr, Hn, Hn);

    k_init<<<(Bn * Hn) / 256, 256, 0, stream>>>(enc, convw, convb, Xhi0, Xlo0, C, mask);

    for (int step = 0; step < Tn; ++step) {
        short* Xh_cur = (step & 1) ? Xhi1 : Xhi0;
        short* Xl_cur = (step & 1) ? Xlo1 : Xlo0;
        short* Xh_nxt = (step & 1) ? Xhi0 : Xhi1;
        short* Xl_nxt = (step & 1) ? Xlo0 : Xlo1;

        // gates GEMM + fused LSTM cell: reads X_cur, writes h into X_next, updates C
        gemm_t<4, true, 1><<<dim3(2048 / 128, Bn / 128), 256, 0, stream>>>(
            Xh_cur, Xl_cur, 1024, WcatHi, WcatLo, bcat, nullptr, C, Xh_nxt, Xl_nxt, 2048, 1024);
        // W2h = h @ W2^T + b2   [4096,512], K=512  (h = X_next[:,512:])
        gemm_t<2, false, 3><<<dim3(Hn / 64, Bn / 128), 256, 0, stream>>>(
            Xh_nxt + 512, Xl_nxt + 512, 1024, W2hi, W2lo, b2, W2h, nullptr, nullptr, nullptr, Hn, Hn);
        // attention, argmax, mask, gather next input into X_next[:,0:512]
        k_attn<<<Bn, 256, 0, stream>>>(W1E, W2h, vw, vb, inps, Xh_nxt, Xl_nxt, mask, probs, ptrs, step);
    }
}

// Round 12
// 879.363 us; speedup vs baseline: 1.0724x; 1.0724x over previous
//
#include <hip/hip_runtime.h>
#include <hip/hip_bf16.h>

#define Bn 4096
#define Tn 8
#define Hn 512

typedef __attribute__((ext_vector_type(8))) _Float16 half8v;
typedef __attribute__((ext_vector_type(4))) float f32x4;

__device__ __forceinline__ float sigm(float x) { return 0.5f * tanhf(0.5f * x) + 0.5f; }

__device__ __forceinline__ short f2h(float x) {
    _Float16 h = (_Float16)x;
    return *reinterpret_cast<short*>(&h);
}
__device__ __forceinline__ float h2f(short s) {
    _Float16 h = *reinterpret_cast<_Float16*>(&s);
    return (float)h;
}
// x ~= hi + lo*2^-12 ; lo pre-scaled by 2^12 so it stays fp16-normal
__device__ __forceinline__ void split2(float x, short& hi, short& lo) {
    hi = f2h(x);
    lo = f2h((x - h2f(hi)) * 4096.0f);
}

#define GLOAD16(g, l) __builtin_amdgcn_global_load_lds( \
    (const __attribute__((address_space(1))) unsigned int*)(g), \
    (__attribute__((address_space(3))) unsigned int*)(l), 16, 0, 0)

// ---------------- setup kernels ----------------

// Wcat rows remapped: j' = (h&15) | (gate<<4) | ((h>>4)<<6), source row = gate*512 + h.
__global__ __launch_bounds__(256) void k_prep(const float* __restrict__ Wih,
                                              const float* __restrict__ Whh,
                                              const float* __restrict__ bih,
                                              const float* __restrict__ bhh,
                                              short* __restrict__ WcatHi,
                                              short* __restrict__ WcatLo,
                                              float* __restrict__ bcat) {
    int tid = blockIdx.x * 256 + threadIdx.x;   // over 2048*1024
    int jp = tid >> 10, k = tid & 1023;
    int g = (jp >> 4) & 3;
    int h = (jp & 15) + ((jp >> 6) << 4);
    int j = g * 512 + h;                        // source row in [Wih|Whh]
    float v = (k < 512) ? Wih[j * 512 + k] : Whh[j * 512 + (k - 512)];
    short hi, lo; split2(v, hi, lo);
    WcatHi[tid] = hi; WcatLo[tid] = lo;
    if (k == 0) bcat[jp] = bih[j] + bhh[j];
}

__global__ __launch_bounds__(256) void k_split4(const float* __restrict__ x,
                                                short* __restrict__ hi,
                                                short* __restrict__ lo, int n4) {
    int i = blockIdx.x * 256 + threadIdx.x;
    if (i >= n4) return;
    float4 v = ((const float4*)x)[i];
    short h0, l0, h1, l1, h2, l2, h3, l3;
    split2(v.x, h0, l0); split2(v.y, h1, l1);
    split2(v.z, h2, l2); split2(v.w, h3, l3);
    ((short4*)hi)[i] = make_short4(h0, h1, h2, h3);
    ((short4*)lo)[i] = make_short4(l0, l1, l2, l3);
}

// inp0 = sum_t enc[b,t,h]*cw[t] + cb ; zero h-part of X0, zero C, zero mask
__global__ __launch_bounds__(256) void k_init(const float* __restrict__ enc,
                                              const float* __restrict__ cw,
                                              const float* __restrict__ cb,
                                              short* __restrict__ Xhi,
                                              short* __restrict__ Xlo,
                                              float* __restrict__ C,
                                              int* __restrict__ mask) {
    int tid = blockIdx.x * 256 + threadIdx.x;   // over B*H
    int b = tid >> 9, h = tid & 511;
    float s = cb[0];
    const float* e = enc + ((size_t)b << 12) + h;
#pragma unroll
    for (int t = 0; t < Tn; ++t) s = fmaf(e[t * Hn], cw[t], s);
    short hi, lo; split2(s, hi, lo);
    size_t xb = ((size_t)b << 10) + h;
    Xhi[xb] = hi; Xlo[xb] = lo;
    Xhi[xb + 512] = 0; Xlo[xb + 512] = 0;
    C[tid] = 0.0f;
    if (h == 0) mask[b] = 0;
}

// ---------------- split-fp16 MFMA GEMM, 8 waves (4x2), dbuf 2-phase ----------------
// C[m,n] = sum_k (Ahi + Alo*2^-12)[m,k] * (Whi + Wlo*2^-12)[n,k] + bias[n]
// BM=128, BN=32*NW, BK=32. 512 threads = 8 waves as 4(m) x 2(n); wave tile
// 32 x (BN/2) -> per-wave col frags NJ = NW (NOT NW/2 -- round-11 bug).
// Same LDS footprint as 4-wave version -> 2 blocks/CU but 4 waves/SIMD (was 2).
// Double-buffered, one __syncthreads per K-step (round-7 proven sync).
// SWZ: bijective XCD-aware blockIdx remap (XCD = linear wgid % 8):
//   1: grid(16,32) -> 8x8 super-tile per XCD   (gates)
//   2: grid(4,256) -> 32 full rows per XCD     (W1E)
//   3: grid(8,32)  -> 8x4 super-tile per XCD   (W2h)
template <int NW, bool FUSE, int SWZ>
__global__ __launch_bounds__(512) void gemm_t(
    const short* __restrict__ Ahi, const short* __restrict__ Alo, int lda,
    const short* __restrict__ Whi, const short* __restrict__ Wlo,
    const float* __restrict__ bias, float* __restrict__ out,
    float* __restrict__ Cst, short* __restrict__ Xh, short* __restrict__ Xl,
    int N, int K) {
    constexpr int BN = 32 * NW;
    constexpr int NJ = NW;                         // col frags per wave (BN/2 cols = NW frags)
    constexpr int BUFSH = 8192 + 2 * BN * 32;      // shorts per buffer (Ahi,Alo,Bhi,Blo)
    __shared__ short sm[2 * BUFSH];

    int bx = blockIdx.x, by = blockIdx.y;
    if constexpr (SWZ == 1) {
        int w = bx + (by << 4), c = w & 7, k = w >> 3;
        by = ((c >> 1) << 3) | (k >> 3);
        bx = ((c & 1) << 3) | (k & 7);
    } else if constexpr (SWZ == 2) {
        int w = bx + (by << 2), c = w & 7, k = w >> 3;
        by = (c << 5) | (k >> 2);
        bx = k & 3;
    } else if constexpr (SWZ == 3) {
        int w = bx + (by << 3), c = w & 7, k = w >> 3;
        by = ((c >> 1) << 3) | (k >> 2);
        bx = ((c & 1) << 2) | (k & 3);
    }

    const int tid = threadIdx.x;
    const int lane = tid & 63;
    const int wv = tid >> 6;                       // 0..7
    const int wm = wv >> 1;                        // 0..3 (row group, 32 rows)
    const int wn = wv & 1;                         // 0..1 (col group, BN/2 cols)
    const int lm = lane & 15, lk = lane >> 4;
    const int m0 = by * 128, n0 = bx * BN;

    f32x4 acc[2][NJ] = {};
    f32x4 acc2[2][NJ] = {};

    float bb[NJ];
#pragma unroll
    for (int j = 0; j < NJ; ++j) bb[j] = bias[n0 + wn * (BN >> 1) + j * 16 + lm];

    // stage tile at k0: 512 threads, 1 chunk each for A hi/lo; B rows=BN
    auto STAGE = [&](int buf, int k0) {
        short* base = sm + buf * BUFSH;
        {
            int row = tid >> 2, sq = tid & 3;
            int qg = sq ^ ((row >> 1) & 3);
            size_t aoff = (size_t)(m0 + row) * lda + k0 + qg * 8;
            GLOAD16(Ahi + aoff, base + tid * 8);
            GLOAD16(Alo + aoff, base + 4096 + tid * 8);
        }
        if (BN == 128 || tid < BN * 4) {           // wave-uniform (waves 0-3 for BN=64)
            int row = tid >> 2, sq = tid & 3;
            int qg = sq ^ ((row >> 1) & 3);
            size_t boff = (size_t)(n0 + row) * K + k0 + qg * 8;
            GLOAD16(Whi + boff, base + 8192 + tid * 8);
            GLOAD16(Wlo + boff, base + 8192 + BN * 32 + tid * 8);
        }
    };

    STAGE(0, 0);
    int cur = 0;
    for (int k0 = 0; k0 < K; k0 += 32) {
        __syncthreads();                           // buf[cur] staged; prev reads done
        if (k0 + 32 < K) STAGE(cur ^ 1, k0 + 32);

        short* base = sm + cur * BUFSH;
        half8v ahi[2], alo[2], bhi[NJ], blo[NJ];
#pragma unroll
        for (int i = 0; i < 2; ++i) {
            int ra = wm * 32 + i * 16 + lm;
            int offa = ra * 32 + (lk ^ ((ra >> 1) & 3)) * 8;
            ahi[i] = *(const half8v*)&base[offa];
            alo[i] = *(const half8v*)&base[4096 + offa];
        }
#pragma unroll
        for (int j = 0; j < NJ; ++j) {
            int rb = wn * (BN >> 1) + j * 16 + lm;
            int offb = rb * 32 + (lk ^ ((rb >> 1) & 3)) * 8;
            bhi[j] = *(const half8v*)&base[8192 + offb];
            blo[j] = *(const half8v*)&base[8192 + BN * 32 + offb];
        }
#pragma unroll
        for (int i = 0; i < 2; ++i)
#pragma unroll
            for (int j = 0; j < NJ; ++j) {
                acc[i][j]  = __builtin_amdgcn_mfma_f32_16x16x32_f16(ahi[i], bhi[j], acc[i][j], 0, 0, 0);
                acc2[i][j] = __builtin_amdgcn_mfma_f32_16x16x32_f16(ahi[i], blo[j], acc2[i][j], 0, 0, 0);
                acc2[i][j] = __builtin_amdgcn_mfma_f32_16x16x32_f16(alo[i], bhi[j], acc2[i][j], 0, 0, 0);
            }
        cur ^= 1;
    }

    const float ls = 1.0f / 4096.0f;

    if constexpr (FUSE) {
        // BN=128, NJ=4: col = n0 + wn*64 + j*16 + lm -> gate = j,
        // h = lm + 16*((n0>>6) + wn)   (identical mapping to round-7 FUSE)
        const int h = lm + 16 * ((n0 >> 6) + wn);
#pragma unroll
        for (int i = 0; i < 2; ++i) {
#pragma unroll
            for (int r = 0; r < 4; ++r) {
                int brow = m0 + wm * 32 + i * 16 + lk * 4 + r;
                float gi = acc[i][0][r] + ls * acc2[i][0][r] + bb[0];
                float gf = acc[i][1][r] + ls * acc2[i][1][r] + bb[1];
                float gg = acc[i][2][r] + ls * acc2[i][2][r] + bb[2];
                float go = acc[i][3][r] + ls * acc2[i][3][r] + bb[3];
                size_t ch = ((size_t)brow << 9) + h;
                float c = sigm(gf) * Cst[ch] + sigm(gi) * tanhf(gg);
                float hn = sigm(go) * tanhf(c);
                Cst[ch] = c;
                short shi, slo; split2(hn, shi, slo);
                size_t xb = ((size_t)brow << 10) + 512 + h;
                Xh[xb] = shi; Xl[xb] = slo;
            }
        }
    } else {
        __syncthreads();                           // all tile reads complete (LDS reuse)
        // LDS-transpose epilogue -> coalesced float4 stores
        constexpr int SW = 16 * NJ + 4;
        float* tile = reinterpret_cast<float*>(sm) + wv * 16 * SW;
        constexpr int LPR = 4 * NJ;                // lanes per row (16B chunks)
        const int rl = lane / LPR, cc = lane % LPR;
#pragma unroll
        for (int i = 0; i < 2; ++i) {
#pragma unroll
            for (int j = 0; j < NJ; ++j)
#pragma unroll
                for (int r = 0; r < 4; ++r)
                    tile[(lk * 4 + r) * SW + j * 16 + lm] = acc[i][j][r] + ls * acc2[i][j][r] + bb[j];
            constexpr int RPS = 64 / LPR;          // rows per sweep
#pragma unroll
            for (int s = 0; s < 16 / RPS; ++s) {
                int row = s * RPS + rl;
                float4 v = *(float4*)&tile[row * SW + cc * 4];
                *(float4*)(out + (size_t)(m0 + wm * 32 + i * 16 + row) * N +
                           n0 + wn * (BN >> 1) + cc * 4) = v;
            }
        }
    }
}

// ---------------- attention + argmax + mask + gather into X_next ----------------
// 4 waves; wave wv owns t = 2*wv and 2*wv+1 (full 512-dot per wave).
__global__ __launch_bounds__(256) void k_attn(const float* __restrict__ W1E,
                                              const float* __restrict__ W2h,
                                              const float* __restrict__ vw,
                                              const float* __restrict__ vbp,
                                              const float* __restrict__ inps,
                                              short* __restrict__ Xhi,
                                              short* __restrict__ Xlo,
                                              int* __restrict__ mask,
                                              float* __restrict__ probs,
                                              float* __restrict__ ptrs,
                                              int step) {
    const int b = blockIdx.x;
    const int tid = threadIdx.x;
    const int lane = tid & 63;
    const int wv = tid >> 6;
    __shared__ float sU[Tn];
    __shared__ int sptr;

    const float4* w2p = (const float4*)(W2h + (size_t)b * Hn + lane * 8);
    float4 w2a = w2p[0], w2b = w2p[1];
    const float4* vp = (const float4*)(vw + lane * 8);
    float4 va = vp[0], vb4 = vp[1];
    float vbias = vbp[0];

#pragma unroll
    for (int q = 0; q < 2; ++q) {
        int t = wv * 2 + q;
        const float4* w1 = (const float4*)(W1E + ((size_t)b << 12) + t * Hn + lane * 8);
        float4 u0 = w1[0], u1 = w1[1];
        float p = va.x * tanhf(u0.x + w2a.x) + va.y * tanhf(u0.y + w2a.y)
                + va.z * tanhf(u0.z + w2a.z) + va.w * tanhf(u0.w + w2a.w)
                + vb4.x * tanhf(u1.x + w2b.x) + vb4.y * tanhf(u1.y + w2b.y)
                + vb4.z * tanhf(u1.z + w2b.z) + vb4.w * tanhf(u1.w + w2b.w);
#pragma unroll
        for (int off = 32; off; off >>= 1) p += __shfl_down(p, off, 64);
        if (lane == 0) sU[t] = p + vbias;
    }
    __syncthreads();

    if (tid == 0) {
        int mk = mask[b];
        float best = -1e30f;
        int ptr = 0;
#pragma unroll
        for (int t = 0; t < Tn; ++t) {
            probs[(size_t)b * 64 + step * 8 + t] = sU[t];
            if (!((mk >> t) & 1) && sU[t] > best) { best = sU[t]; ptr = t; }
        }
        mask[b] = mk | (1 << ptr);
        ptrs[(size_t)b * 8 + step] = (float)ptr;
        sptr = ptr;
    }
    __syncthreads();
    const float2* src = (const float2*)(inps + ((size_t)b << 12) + (size_t)sptr * Hn);
    float2 v = src[tid];
    short h0, l0, h1, l1;
    split2(v.x, h0, l0); split2(v.y, h1, l1);
    size_t xb = ((size_t)b << 10) + tid * 2;
    *(short2*)&Xhi[xb] = make_short2(h0, h1);
    *(short2*)&Xlo[xb] = make_short2(l0, l1);
}

// ---------------- launch ----------------
extern "C" void kernel_launch(void* const* d_in, const int* in_sizes, int n_in,
                              void* d_out, int out_size, void* d_ws, size_t ws_size,
                              hipStream_t stream) {
    const float* inps  = (const float*)d_in[0];
    const float* enc   = (const float*)d_in[1];
    const float* convw = (const float*)d_in[2];
    const float* convb = (const float*)d_in[3];
    const float* Wih   = (const float*)d_in[4];
    const float* Whh   = (const float*)d_in[5];
    const float* bih   = (const float*)d_in[6];
    const float* bhh   = (const float*)d_in[7];
    const float* W1    = (const float*)d_in[8];
    const float* b1    = (const float*)d_in[9];
    const float* W2    = (const float*)d_in[10];
    const float* b2    = (const float*)d_in[11];
    const float* vw    = (const float*)d_in[12];
    const float* vb    = (const float*)d_in[13];

    float* out   = (float*)d_out;
    float* probs = out;                       // [B, 8, 8]
    float* ptrs  = out + (size_t)Bn * 64;     // [B, 8] as float

    char* wsb = (char*)d_ws;
    float* W1E    = (float*)wsb;                          // [0,64MB) fp32 [B*T,512]
    short* encHi  = (short*)(wsb + (64ull << 20));        // dead after W1E gemm
    short* encLo  = (short*)(wsb + (96ull << 20));        // dead after W1E gemm
    short* Xhi1   = (short*)(wsb + (64ull << 20));        // 8MB fp16 [B,1024]
    short* Xlo1   = (short*)(wsb + (72ull << 20));        // 8MB
    float* W2h    = (float*)(wsb + (96ull << 20));        // 8MB fp32 [B,512]
    float* C      = (float*)(wsb + (104ull << 20));       // 8MB fp32 [B,512]
    short* Xhi0   = (short*)(wsb + (112ull << 20));       // 8MB
    short* Xlo0   = (short*)(wsb + (120ull << 20));       // 8MB
    short* WcatHi = (short*)(wsb + (128ull << 20));       // 4MB [2048,1024]
    short* WcatLo = (short*)(wsb + (132ull << 20));       // 4MB
    short* W1hi   = (short*)(wsb + (136ull << 20));
    short* W1lo   = (short*)(wsb + (136ull << 20) + (512u << 10));
    short* W2hi   = (short*)(wsb + (137ull << 20));
    short* W2lo   = (short*)(wsb + (137ull << 20) + (512u << 10));
    float* bcat   = (float*)(wsb + (138ull << 20));
    int*   mask   = (int*)(wsb + (138ull << 20) + (16u << 10));

    k_prep<<<(2048 * 1024) / 256, 256, 0, stream>>>(Wih, Whh, bih, bhh, WcatHi, WcatLo, bcat);
    k_split4<<<(Bn * Tn * Hn / 4) / 256, 256, 0, stream>>>(enc, encHi, encLo, Bn * Tn * Hn / 4);
    k_split4<<<(Hn * Hn / 4) / 256, 256, 0, stream>>>(W1, W1hi, W1lo, Hn * Hn / 4);
    k_split4<<<(Hn * Hn / 4) / 256, 256, 0, stream>>>(W2, W2hi, W2lo, Hn * Hn / 4);

    // W1E = enc @ W1^T + b1   [B*T, 512], K=512
    gemm_t<4, false, 2><<<dim3(Hn / 128, (Bn * Tn) / 128), 512, 0, stream>>>(
        encHi, encLo, Hn, W1hi, W1lo, b1, W1E, nullptr, nullptr, nullptr, Hn, Hn);

    k_init<<<(Bn * Hn) / 256, 256, 0, stream>>>(enc, convw, convb, Xhi0, Xlo0, C, mask);

    for (int step = 0; step < Tn; ++step) {
        short* Xh_cur = (step & 1) ? Xhi1 : Xhi0;
        short* Xl_cur = (step & 1) ? Xlo1 : Xlo0;
        short* Xh_nxt = (step & 1) ? Xhi0 : Xhi1;
        short* Xl_nxt = (step & 1) ? Xlo0 : Xlo1;

        // gates GEMM + fused LSTM cell: reads X_cur, writes h into X_next, updates C
        gemm_t<4, true, 1><<<dim3(2048 / 128, Bn / 128), 512, 0, stream>>>(
            Xh_cur, Xl_cur, 1024, WcatHi, WcatLo, bcat, nullptr, C, Xh_nxt, Xl_nxt, 2048, 1024);
        // W2h = h @ W2^T + b2   [4096,512], K=512  (h = X_next[:,512:])
        gemm_t<2, false, 3><<<dim3(Hn / 64, Bn / 128), 512, 0, stream>>>(
            Xh_nxt + 512, Xl_nxt + 512, 1024, W2hi, W2lo, b2, W2h, nullptr, nullptr, nullptr, Hn, Hn);
        // attention, argmax, mask, gather next input into X_next[:,0:512]
        k_attn<<<Bn, 256, 0, stream>>>(W1E, W2h, vw, vb, inps, Xh_nxt, Xl_nxt, mask, probs, ptrs, step);
    }
}

// Round 13
// 873.399 us; speedup vs baseline: 1.0798x; 1.0068x over previous
//
#include <hip/hip_runtime.h>
#include <hip/hip_bf16.h>

#define Bn 4096
#define Tn 8
#define Hn 512

typedef __attribute__((ext_vector_type(8))) _Float16 half8v;
typedef __attribute__((ext_vector_type(4))) float f32x4;

__device__ __forceinline__ float sigm(float x) { return 0.5f * tanhf(0.5f * x) + 0.5f; }

__device__ __forceinline__ short f2h(float x) {
    _Float16 h = (_Float16)x;
    return *reinterpret_cast<short*>(&h);
}
__device__ __forceinline__ float h2f(short s) {
    _Float16 h = *reinterpret_cast<_Float16*>(&s);
    return (float)h;
}
// x ~= hi + lo*2^-12 ; lo pre-scaled by 2^12 so it stays fp16-normal
__device__ __forceinline__ void split2(float x, short& hi, short& lo) {
    hi = f2h(x);
    lo = f2h((x - h2f(hi)) * 4096.0f);
}

#define GLOAD16(g, l) __builtin_amdgcn_global_load_lds( \
    (const __attribute__((address_space(1))) unsigned int*)(g), \
    (__attribute__((address_space(3))) unsigned int*)(l), 16, 0, 0)

// ---------------- setup kernels ----------------

// Wcat rows remapped: j' = (h&15) | (gate<<4) | ((h>>4)<<6), source row = gate*512 + h.
__global__ __launch_bounds__(256) void k_prep(const float* __restrict__ Wih,
                                              const float* __restrict__ Whh,
                                              const float* __restrict__ bih,
                                              const float* __restrict__ bhh,
                                              short* __restrict__ WcatHi,
                                              short* __restrict__ WcatLo,
                                              float* __restrict__ bcat) {
    int tid = blockIdx.x * 256 + threadIdx.x;   // over 2048*1024
    int jp = tid >> 10, k = tid & 1023;
    int g = (jp >> 4) & 3;
    int h = (jp & 15) + ((jp >> 6) << 4);
    int j = g * 512 + h;                        // source row in [Wih|Whh]
    float v = (k < 512) ? Wih[j * 512 + k] : Whh[j * 512 + (k - 512)];
    short hi, lo; split2(v, hi, lo);
    WcatHi[tid] = hi; WcatLo[tid] = lo;
    if (k == 0) bcat[jp] = bih[j] + bhh[j];
}

__global__ __launch_bounds__(256) void k_split4(const float* __restrict__ x,
                                                short* __restrict__ hi,
                                                short* __restrict__ lo, int n4) {
    int i = blockIdx.x * 256 + threadIdx.x;
    if (i >= n4) return;
    float4 v = ((const float4*)x)[i];
    short h0, l0, h1, l1, h2, l2, h3, l3;
    split2(v.x, h0, l0); split2(v.y, h1, l1);
    split2(v.z, h2, l2); split2(v.w, h3, l3);
    ((short4*)hi)[i] = make_short4(h0, h1, h2, h3);
    ((short4*)lo)[i] = make_short4(l0, l1, l2, l3);
}

// inp0 = sum_t enc[b,t,h]*cw[t] + cb ; zero h-part of X0, zero C, zero mask
__global__ __launch_bounds__(256) void k_init(const float* __restrict__ enc,
                                              const float* __restrict__ cw,
                                              const float* __restrict__ cb,
                                              short* __restrict__ Xhi,
                                              short* __restrict__ Xlo,
                                              float* __restrict__ C,
                                              int* __restrict__ mask) {
    int tid = blockIdx.x * 256 + threadIdx.x;   // over B*H
    int b = tid >> 9, h = tid & 511;
    float s = cb[0];
    const float* e = enc + ((size_t)b << 12) + h;
#pragma unroll
    for (int t = 0; t < Tn; ++t) s = fmaf(e[t * Hn], cw[t], s);
    short hi, lo; split2(s, hi, lo);
    size_t xb = ((size_t)b << 10) + h;
    Xhi[xb] = hi; Xlo[xb] = lo;
    Xhi[xb + 512] = 0; Xlo[xb + 512] = 0;
    C[tid] = 0.0f;
    if (h == 0) mask[b] = 0;
}

// ---------------- split-fp16 MFMA GEMM, 8 waves (4x2), counted-vmcnt depth-2 ---------
// C[m,n] = sum_k (Ahi + Alo*2^-12)[m,k] * (Whi + Wlo*2^-12)[n,k] + bias[n]
// BM=128, BN=32*NW, BK=32. 512 threads = 8 waves as 4(m) x 2(n); wave tile
// 32 x (BN/2), per-wave col frags NJ = NW. Uniform loads/thread/stage:
// NW=4 -> 4 (Ahi,Alo,Bhi,Blo); NW=2 -> 3 (Ahi,Alo,+B-half split across thread halves).
// Sync per K-step: vmcnt(L) [never 0 until last]; barrier; ds_read; lgkmcnt(0);
// barrier; STAGE(kt+2); MFMA. Depth-2 prefetch keeps 2L loads in flight.
// SWZ: bijective XCD-aware blockIdx remap (XCD = linear wgid % 8):
//   1: grid(16,32) -> 8x8 super-tile per XCD   (gates)
//   2: grid(4,256) -> 32 full rows per XCD     (W1E)
//   3: grid(8,32)  -> 8x4 super-tile per XCD   (W2h)
template <int NW, bool FUSE, int SWZ>
__global__ __launch_bounds__(512) void gemm_t(
    const short* __restrict__ Ahi, const short* __restrict__ Alo, int lda,
    const short* __restrict__ Whi, const short* __restrict__ Wlo,
    const float* __restrict__ bias, float* __restrict__ out,
    float* __restrict__ Cst, short* __restrict__ Xh, short* __restrict__ Xl,
    int N, int K) {
    constexpr int BN = 32 * NW;
    constexpr int NJ = NW;                         // col frags per wave (BN/2 cols)
    constexpr int BUFSH = 8192 + 2 * BN * 32;      // shorts per buffer (Ahi,Alo,Bhi,Blo)
    __shared__ short sm[2 * BUFSH];

    int bx = blockIdx.x, by = blockIdx.y;
    if constexpr (SWZ == 1) {
        int w = bx + (by << 4), c = w & 7, k = w >> 3;
        by = ((c >> 1) << 3) | (k >> 3);
        bx = ((c & 1) << 3) | (k & 7);
    } else if constexpr (SWZ == 2) {
        int w = bx + (by << 2), c = w & 7, k = w >> 3;
        by = (c << 5) | (k >> 2);
        bx = k & 3;
    } else if constexpr (SWZ == 3) {
        int w = bx + (by << 3), c = w & 7, k = w >> 3;
        by = ((c >> 1) << 3) | (k >> 2);
        bx = ((c & 1) << 2) | (k & 3);
    }

    const int tid = threadIdx.x;
    const int lane = tid & 63;
    const int wv = tid >> 6;                       // 0..7
    const int wm = wv >> 1;                        // 0..3 (row group, 32 rows)
    const int wn = wv & 1;                         // 0..1 (col group, BN/2 cols)
    const int lm = lane & 15, lk = lane >> 4;
    const int m0 = by * 128, n0 = bx * BN;

    f32x4 acc[2][NJ] = {};
    f32x4 acc2[2][NJ] = {};

    float bb[NJ];
#pragma unroll
    for (int j = 0; j < NJ; ++j) bb[j] = bias[n0 + wn * (BN >> 1) + j * 16 + lm];

    // stage tile at k0: uniform loads per thread (4 for NW=4, 3 for NW=2)
    auto STAGE = [&](int buf, int k0) {
        short* base = sm + buf * BUFSH;
        {
            int row = tid >> 2, sq = tid & 3;
            int qg = sq ^ ((row >> 1) & 3);
            size_t aoff = (size_t)(m0 + row) * lda + k0 + qg * 8;
            GLOAD16(Ahi + aoff, base + tid * 8);
            GLOAD16(Alo + aoff, base + 4096 + tid * 8);
        }
        if constexpr (NW == 4) {
            int row = tid >> 2, sq = tid & 3;
            int qg = sq ^ ((row >> 1) & 3);
            size_t boff = (size_t)(n0 + row) * K + k0 + qg * 8;
            GLOAD16(Whi + boff, base + 8192 + tid * 8);
            GLOAD16(Wlo + boff, base + 8192 + BN * 32 + tid * 8);
        } else {
            // BN=64: 256 chunks; threads 0-255 -> Bhi, threads 256-511 -> Blo
            int t2 = tid & 255;
            int row = t2 >> 2, sq = t2 & 3;
            int qg = sq ^ ((row >> 1) & 3);
            size_t boff = (size_t)(n0 + row) * K + k0 + qg * 8;
            const short* src = (tid < 256) ? (Whi + boff) : (Wlo + boff);
            short* dst = base + 8192 + ((tid < 256) ? 0 : BN * 32) + t2 * 8;
            GLOAD16(src, dst);
        }
    };

    const int nkt = K >> 5;
    // drain bias loads so counted vmcnt waits below are exact
    asm volatile("s_waitcnt vmcnt(0)" ::: "memory");
    __builtin_amdgcn_sched_barrier(0);
    STAGE(0, 0);
    STAGE(1, 32);

    for (int kt = 0; kt < nkt; ++kt) {
        const int cur = kt & 1;
        // wait for buf[cur]'s stage (the oldest L loads); newer stage keeps flying
        if (kt == nkt - 1) {
            asm volatile("s_waitcnt vmcnt(0)" ::: "memory");
        } else {
            if constexpr (NW == 4) asm volatile("s_waitcnt vmcnt(4)" ::: "memory");
            else                   asm volatile("s_waitcnt vmcnt(3)" ::: "memory");
        }
        __builtin_amdgcn_s_barrier();              // all waves' buf[cur] writes visible
        __builtin_amdgcn_sched_barrier(0);         // pin: no ds_read above this point

        short* base = sm + cur * BUFSH;
        half8v ahi[2], alo[2], bhi[NJ], blo[NJ];
#pragma unroll
        for (int i = 0; i < 2; ++i) {
            int ra = wm * 32 + i * 16 + lm;
            int offa = ra * 32 + (lk ^ ((ra >> 1) & 3)) * 8;
            ahi[i] = *(const half8v*)&base[offa];
            alo[i] = *(const half8v*)&base[4096 + offa];
        }
#pragma unroll
        for (int j = 0; j < NJ; ++j) {
            int rb = wn * (BN >> 1) + j * 16 + lm;
            int offb = rb * 32 + (lk ^ ((rb >> 1) & 3)) * 8;
            bhi[j] = *(const half8v*)&base[8192 + offb];
            blo[j] = *(const half8v*)&base[8192 + BN * 32 + offb];
        }
        asm volatile("s_waitcnt lgkmcnt(0)" ::: "memory");  // my ds_reads done
        __builtin_amdgcn_sched_barrier(0);
        __builtin_amdgcn_s_barrier();              // ALL waves' reads done -> safe restage
        __builtin_amdgcn_sched_barrier(0);         // pin: STAGE stays below barrier
        if (kt + 2 < nkt) STAGE(cur, (kt + 2) * 32);

#pragma unroll
        for (int i = 0; i < 2; ++i)
#pragma unroll
            for (int j = 0; j < NJ; ++j) {
                acc[i][j]  = __builtin_amdgcn_mfma_f32_16x16x32_f16(ahi[i], bhi[j], acc[i][j], 0, 0, 0);
                acc2[i][j] = __builtin_amdgcn_mfma_f32_16x16x32_f16(ahi[i], blo[j], acc2[i][j], 0, 0, 0);
                acc2[i][j] = __builtin_amdgcn_mfma_f32_16x16x32_f16(alo[i], bhi[j], acc2[i][j], 0, 0, 0);
            }
    }

    const float ls = 1.0f / 4096.0f;

    if constexpr (FUSE) {
        // BN=128, NJ=4: col = n0 + wn*64 + j*16 + lm -> gate = j,
        // h = lm + 16*((n0>>6) + wn)
        const int h = lm + 16 * ((n0 >> 6) + wn);
#pragma unroll
        for (int i = 0; i < 2; ++i) {
#pragma unroll
            for (int r = 0; r < 4; ++r) {
                int brow = m0 + wm * 32 + i * 16 + lk * 4 + r;
                float gi = acc[i][0][r] + ls * acc2[i][0][r] + bb[0];
                float gf = acc[i][1][r] + ls * acc2[i][1][r] + bb[1];
                float gg = acc[i][2][r] + ls * acc2[i][2][r] + bb[2];
                float go = acc[i][3][r] + ls * acc2[i][3][r] + bb[3];
                size_t ch = ((size_t)brow << 9) + h;
                float c = sigm(gf) * Cst[ch] + sigm(gi) * tanhf(gg);
                float hn = sigm(go) * tanhf(c);
                Cst[ch] = c;
                short shi, slo; split2(hn, shi, slo);
                size_t xb = ((size_t)brow << 10) + 512 + h;
                Xh[xb] = shi; Xl[xb] = slo;
            }
        }
    } else {
        __syncthreads();                           // all tile reads complete (LDS reuse)
        // LDS-transpose epilogue -> coalesced float4 stores
        constexpr int SW = 16 * NJ + 4;
        float* tile = reinterpret_cast<float*>(sm) + wv * 16 * SW;
        constexpr int LPR = 4 * NJ;                // lanes per row (16B chunks)
        const int rl = lane / LPR, cc = lane % LPR;
#pragma unroll
        for (int i = 0; i < 2; ++i) {
#pragma unroll
            for (int j = 0; j < NJ; ++j)
#pragma unroll
                for (int r = 0; r < 4; ++r)
                    tile[(lk * 4 + r) * SW + j * 16 + lm] = acc[i][j][r] + ls * acc2[i][j][r] + bb[j];
            constexpr int RPS = 64 / LPR;          // rows per sweep
#pragma unroll
            for (int s = 0; s < 16 / RPS; ++s) {
                int row = s * RPS + rl;
                float4 v = *(float4*)&tile[row * SW + cc * 4];
                *(float4*)(out + (size_t)(m0 + wm * 32 + i * 16 + row) * N +
                           n0 + wn * (BN >> 1) + cc * 4) = v;
            }
        }
    }
}

// ---------------- attention + argmax + mask + gather into X_next ----------------
// 4 waves; wave wv owns t = 2*wv and 2*wv+1 (full 512-dot per wave).
__global__ __launch_bounds__(256) void k_attn(const float* __restrict__ W1E,
                                              const float* __restrict__ W2h,
                                              const float* __restrict__ vw,
                                              const float* __restrict__ vbp,
                                              const float* __restrict__ inps,
                                              short* __restrict__ Xhi,
                                              short* __restrict__ Xlo,
                                              int* __restrict__ mask,
                                              float* __restrict__ probs,
                                              float* __restrict__ ptrs,
                                              int step) {
    const int b = blockIdx.x;
    const int tid = threadIdx.x;
    const int lane = tid & 63;
    const int wv = tid >> 6;
    __shared__ float sU[Tn];
    __shared__ int sptr;

    const float4* w2p = (const float4*)(W2h + (size_t)b * Hn + lane * 8);
    float4 w2a = w2p[0], w2b = w2p[1];
    const float4* vp = (const float4*)(vw + lane * 8);
    float4 va = vp[0], vb4 = vp[1];
    float vbias = vbp[0];

#pragma unroll
    for (int q = 0; q < 2; ++q) {
        int t = wv * 2 + q;
        const float4* w1 = (const float4*)(W1E + ((size_t)b << 12) + t * Hn + lane * 8);
        float4 u0 = w1[0], u1 = w1[1];
        float p = va.x * tanhf(u0.x + w2a.x) + va.y * tanhf(u0.y + w2a.y)
                + va.z * tanhf(u0.z + w2a.z) + va.w * tanhf(u0.w + w2a.w)
                + vb4.x * tanhf(u1.x + w2b.x) + vb4.y * tanhf(u1.y + w2b.y)
                + vb4.z * tanhf(u1.z + w2b.z) + vb4.w * tanhf(u1.w + w2b.w);
#pragma unroll
        for (int off = 32; off; off >>= 1) p += __shfl_down(p, off, 64);
        if (lane == 0) sU[t] = p + vbias;
    }
    __syncthreads();

    if (tid == 0) {
        int mk = mask[b];
        float best = -1e30f;
        int ptr = 0;
#pragma unroll
        for (int t = 0; t < Tn; ++t) {
            probs[(size_t)b * 64 + step * 8 + t] = sU[t];
            if (!((mk >> t) & 1) && sU[t] > best) { best = sU[t]; ptr = t; }
        }
        mask[b] = mk | (1 << ptr);
        ptrs[(size_t)b * 8 + step] = (float)ptr;
        sptr = ptr;
    }
    __syncthreads();
    const float2* src = (const float2*)(inps + ((size_t)b << 12) + (size_t)sptr * Hn);
    float2 v = src[tid];
    short h0, l0, h1, l1;
    split2(v.x, h0, l0); split2(v.y, h1, l1);
    size_t xb = ((size_t)b << 10) + tid * 2;
    *(short2*)&Xhi[xb] = make_short2(h0, h1);
    *(short2*)&Xlo[xb] = make_short2(l0, l1);
}

// ---------------- launch ----------------
extern "C" void kernel_launch(void* const* d_in, const int* in_sizes, int n_in,
                              void* d_out, int out_size, void* d_ws, size_t ws_size,
                              hipStream_t stream) {
    const float* inps  = (const float*)d_in[0];
    const float* enc   = (const float*)d_in[1];
    const float* convw = (const float*)d_in[2];
    const float* convb = (const float*)d_in[3];
    const float* Wih   = (const float*)d_in[4];
    const float* Whh   = (const float*)d_in[5];
    const float* bih   = (const float*)d_in[6];
    const float* bhh   = (const float*)d_in[7];
    const float* W1    = (const float*)d_in[8];
    const float* b1    = (const float*)d_in[9];
    const float* W2    = (const float*)d_in[10];
    const float* b2    = (const float*)d_in[11];
    const float* vw    = (const float*)d_in[12];
    const float* vb    = (const float*)d_in[13];

    float* out   = (float*)d_out;
    float* probs = out;                       // [B, 8, 8]
    float* ptrs  = out + (size_t)Bn * 64;     // [B, 8] as float

    char* wsb = (char*)d_ws;
    float* W1E    = (float*)wsb;                          // [0,64MB) fp32 [B*T,512]
    short* encHi  = (short*)(wsb + (64ull << 20));        // dead after W1E gemm
    short* encLo  = (short*)(wsb + (96ull << 20));        // dead after W1E gemm
    short* Xhi1   = (short*)(wsb + (64ull << 20));        // 8MB fp16 [B,1024]
    short* Xlo1   = (short*)(wsb + (72ull << 20));        // 8MB
    float* W2h    = (float*)(wsb + (96ull << 20));        // 8MB fp32 [B,512]
    float* C      = (float*)(wsb + (104ull << 20));       // 8MB fp32 [B,512]
    short* Xhi0   = (short*)(wsb + (112ull << 20));       // 8MB
    short* Xlo0   = (short*)(wsb + (120ull << 20));       // 8MB
    short* WcatHi = (short*)(wsb + (128ull << 20));       // 4MB [2048,1024]
    short* WcatLo = (short*)(wsb + (132ull << 20));       // 4MB
    short* W1hi   = (short*)(wsb + (136ull << 20));
    short* W1lo   = (short*)(wsb + (136ull << 20) + (512u << 10));
    short* W2hi   = (short*)(wsb + (137ull << 20));
    short* W2lo   = (short*)(wsb + (137ull << 20) + (512u << 10));
    float* bcat   = (float*)(wsb + (138ull << 20));
    int*   mask   = (int*)(wsb + (138ull << 20) + (16u << 10));

    k_prep<<<(2048 * 1024) / 256, 256, 0, stream>>>(Wih, Whh, bih, bhh, WcatHi, WcatLo, bcat);
    k_split4<<<(Bn * Tn * Hn / 4) / 256, 256, 0, stream>>>(enc, encHi, encLo, Bn * Tn * Hn / 4);
    k_split4<<<(Hn * Hn / 4) / 256, 256, 0, stream>>>(W1, W1hi, W1lo, Hn * Hn / 4);
    k_split4<<<(Hn * Hn / 4) / 256, 256, 0, stream>>>(W2, W2hi, W2lo, Hn * Hn / 4);

    // W1E = enc @ W1^T + b1   [B*T, 512], K=512
    gemm_t<4, false, 2><<<dim3(Hn / 128, (Bn * Tn) / 128), 512, 0, stream>>>(
        encHi, encLo, Hn, W1hi, W1lo, b1, W1E, nullptr, nullptr, nullptr, Hn, Hn);

    k_init<<<(Bn * Hn) / 256, 256, 0, stream>>>(enc, convw, convb, Xhi0, Xlo0, C, mask);

    for (int step = 0; step < Tn; ++step) {
        short* Xh_cur = (step & 1) ? Xhi1 : Xhi0;
        short* Xl_cur = (step & 1) ? Xlo1 : Xlo0;
        short* Xh_nxt = (step & 1) ? Xhi0 : Xhi1;
        short* Xl_nxt = (step & 1) ? Xlo0 : Xlo1;

        // gates GEMM + fused LSTM cell: reads X_cur, writes h into X_next, updates C
        gemm_t<4, true, 1><<<dim3(2048 / 128, Bn / 128), 512, 0, stream>>>(
            Xh_cur, Xl_cur, 1024, WcatHi, WcatLo, bcat, nullptr, C, Xh_nxt, Xl_nxt, 2048, 1024);
        // W2h = h @ W2^T + b2   [4096,512], K=512  (h = X_next[:,512:])
        gemm_t<2, false, 3><<<dim3(Hn / 64, Bn / 128), 512, 0, stream>>>(
            Xh_nxt + 512, Xl_nxt + 512, 1024, W2hi, W2lo, b2, W2h, nullptr, nullptr, nullptr, Hn, Hn);
        // attention, argmax, mask, gather next input into X_next[:,0:512]
        k_attn<<<Bn, 256, 0, stream>>>(W1E, W2h, vw, vb, inps, Xh_nxt, Xl_nxt, mask, probs, ptrs, step);
    }
}

// Round 15
// 854.622 us; speedup vs baseline: 1.1035x; 1.0220x over previous
//
#include <hip/hip_runtime.h>
#include <hip/hip_bf16.h>

#define Bn 4096
#define Tn 8
#define Hn 512

typedef __attribute__((ext_vector_type(8))) _Float16 half8v;
typedef __attribute__((ext_vector_type(4))) float f32x4;

__device__ __forceinline__ float sigm(float x) { return 0.5f * tanhf(0.5f * x) + 0.5f; }

__device__ __forceinline__ short f2h(float x) {
    _Float16 h = (_Float16)x;
    return *reinterpret_cast<short*>(&h);
}
__device__ __forceinline__ float h2f(short s) {
    _Float16 h = *reinterpret_cast<_Float16*>(&s);
    return (float)h;
}
// x ~= hi + lo*2^-12 ; lo pre-scaled by 2^12 so it stays fp16-normal
__device__ __forceinline__ void split2(float x, short& hi, short& lo) {
    hi = f2h(x);
    lo = f2h((x - h2f(hi)) * 4096.0f);
}

#define GLOAD16(g, l) __builtin_amdgcn_global_load_lds( \
    (const __attribute__((address_space(1))) unsigned int*)(g), \
    (__attribute__((address_space(3))) unsigned int*)(l), 16, 0, 0)

// ---------------- setup kernels ----------------

// Wcat rows remapped: j' = (h&15) | (gate<<4) | ((h>>4)<<6), source row = gate*512 + h.
// Cols 0:511 = Wih, cols 512:1023 = Whh  (so a K=512 loop over Wcat = Wih-only).
__global__ __launch_bounds__(256) void k_prep(const float* __restrict__ Wih,
                                              const float* __restrict__ Whh,
                                              const float* __restrict__ bih,
                                              const float* __restrict__ bhh,
                                              short* __restrict__ WcatHi,
                                              short* __restrict__ WcatLo,
                                              float* __restrict__ bcat) {
    int tid = blockIdx.x * 256 + threadIdx.x;   // over 2048*1024
    int jp = tid >> 10, k = tid & 1023;
    int g = (jp >> 4) & 3;
    int h = (jp & 15) + ((jp >> 6) << 4);
    int j = g * 512 + h;                        // source row in [Wih|Whh]
    float v = (k < 512) ? Wih[j * 512 + k] : Whh[j * 512 + (k - 512)];
    short hi, lo; split2(v, hi, lo);
    WcatHi[tid] = hi; WcatLo[tid] = lo;
    if (k == 0) bcat[jp] = bih[j] + bhh[j];
}

__global__ __launch_bounds__(256) void k_split4(const float* __restrict__ x,
                                                short* __restrict__ hi,
                                                short* __restrict__ lo, int n4) {
    int i = blockIdx.x * 256 + threadIdx.x;
    if (i >= n4) return;
    float4 v = ((const float4*)x)[i];
    short h0, l0, h1, l1, h2, l2, h3, l3;
    split2(v.x, h0, l0); split2(v.y, h1, l1);
    split2(v.z, h2, l2); split2(v.w, h3, l3);
    ((short4*)hi)[i] = make_short4(h0, h1, h2, h3);
    ((short4*)lo)[i] = make_short4(l0, l1, l2, l3);
}

// inp0 = sum_t enc[b,t,h]*cw[t] + cb ; zero h-part of X0, zero C, zero mask.
// NOTE: writes alias the encLo region -> MUST be launched AFTER the W1E gemm.
__global__ __launch_bounds__(256) void k_init(const float* __restrict__ enc,
                                              const float* __restrict__ cw,
                                              const float* __restrict__ cb,
                                              short* __restrict__ Xhi,
                                              short* __restrict__ Xlo,
                                              float* __restrict__ C,
                                              int* __restrict__ mask) {
    int tid = blockIdx.x * 256 + threadIdx.x;   // over B*H
    int b = tid >> 9, h = tid & 511;
    float s = cb[0];
    const float* e = enc + ((size_t)b << 12) + h;
#pragma unroll
    for (int t = 0; t < Tn; ++t) s = fmaf(e[t * Hn], cw[t], s);
    short hi, lo; split2(s, hi, lo);
    size_t xb = ((size_t)b << 10) + h;
    Xhi[xb] = hi; Xlo[xb] = lo;
    Xhi[xb + 512] = 0; Xlo[xb + 512] = 0;
    C[tid] = 0.0f;
    if (h == 0) mask[b] = 0;
}

// ---------------- split-fp16 MFMA GEMM, 8 waves (4x2), dbuf 2-phase ----------------
// C[m,n] = sum_{k<K} (Ahi + Alo*2^-12)[m,k] * (Whi + Wlo*2^-12)[n,k] + bias[n]
// BM=128, BN=32*NW, BK=32. 512 threads = 8 waves as 4(m) x 2(n); wave tile
// 32 x (BN/2), per-wave col frags NJ = NW. wstr = W row stride (may exceed K:
// gates step 0 uses K=512 over Wcat rows of stride 1024 = Wih-only part; h==0
// at step 0 so skipping the Whh half is bit-identical).
// Plain __syncthreads 2-phase (round-12 proven; counted-vmcnt measured null).
// SWZ: bijective XCD-aware blockIdx remap (XCD = linear wgid % 8):
//   1: grid(16,32) -> 8x8 super-tile per XCD   (gates)
//   2: grid(4,256) -> 32 full rows per XCD     (W1E)
//   3: grid(8,32)  -> 8x4 super-tile per XCD   (W2h)
template <int NW, bool FUSE, int SWZ>
__global__ __launch_bounds__(512) void gemm_t(
    const short* __restrict__ Ahi, const short* __restrict__ Alo, int lda,
    const short* __restrict__ Whi, const short* __restrict__ Wlo, int wstr,
    const float* __restrict__ bias, float* __restrict__ out,
    float* __restrict__ Cst, short* __restrict__ Xh, short* __restrict__ Xl,
    int N, int K) {
    constexpr int BN = 32 * NW;
    constexpr int NJ = NW;                         // col frags per wave (BN/2 cols)
    constexpr int BUFSH = 8192 + 2 * BN * 32;      // shorts per buffer (Ahi,Alo,Bhi,Blo)
    __shared__ short sm[2 * BUFSH];

    int bx = blockIdx.x, by = blockIdx.y;
    if constexpr (SWZ == 1) {
        int w = bx + (by << 4), c = w & 7, k = w >> 3;
        by = ((c >> 1) << 3) | (k >> 3);
        bx = ((c & 1) << 3) | (k & 7);
    } else if constexpr (SWZ == 2) {
        int w = bx + (by << 2), c = w & 7, k = w >> 3;
        by = (c << 5) | (k >> 2);
        bx = k & 3;
    } else if constexpr (SWZ == 3) {
        int w = bx + (by << 3), c = w & 7, k = w >> 3;
        by = ((c >> 1) << 3) | (k >> 2);
        bx = ((c & 1) << 2) | (k & 3);
    }

    const int tid = threadIdx.x;
    const int lane = tid & 63;
    const int wv = tid >> 6;                       // 0..7
    const int wm = wv >> 1;                        // 0..3 (row group, 32 rows)
    const int wn = wv & 1;                         // 0..1 (col group, BN/2 cols)
    const int lm = lane & 15, lk = lane >> 4;
    const int m0 = by * 128, n0 = bx * BN;

    f32x4 acc[2][NJ] = {};
    f32x4 acc2[2][NJ] = {};

    float bb[NJ];
#pragma unroll
    for (int j = 0; j < NJ; ++j) bb[j] = bias[n0 + wn * (BN >> 1) + j * 16 + lm];

    // stage tile at k0: pre-swizzled source, linear LDS dest
    auto STAGE = [&](int buf, int k0) {
        short* base = sm + buf * BUFSH;
        {
            int row = tid >> 2, sq = tid & 3;
            int qg = sq ^ ((row >> 1) & 3);
            size_t aoff = (size_t)(m0 + row) * lda + k0 + qg * 8;
            GLOAD16(Ahi + aoff, base + tid * 8);
            GLOAD16(Alo + aoff, base + 4096 + tid * 8);
        }
        if constexpr (NW == 4) {
            int row = tid >> 2, sq = tid & 3;
            int qg = sq ^ ((row >> 1) & 3);
            size_t boff = (size_t)(n0 + row) * wstr + k0 + qg * 8;
            GLOAD16(Whi + boff, base + 8192 + tid * 8);
            GLOAD16(Wlo + boff, base + 8192 + BN * 32 + tid * 8);
        } else {
            // BN=64: 256 chunks; threads 0-255 -> Bhi, threads 256-511 -> Blo
            int t2 = tid & 255;
            int row = t2 >> 2, sq = t2 & 3;
            int qg = sq ^ ((row >> 1) & 3);
            size_t boff = (size_t)(n0 + row) * wstr + k0 + qg * 8;
            const short* src = (tid < 256) ? (Whi + boff) : (Wlo + boff);
            short* dst = base + 8192 + ((tid < 256) ? 0 : BN * 32) + t2 * 8;
            GLOAD16(src, dst);
        }
    };

    STAGE(0, 0);
    int cur = 0;
    for (int k0 = 0; k0 < K; k0 += 32) {
        __syncthreads();                           // buf[cur] staged; prev reads done
        if (k0 + 32 < K) STAGE(cur ^ 1, k0 + 32);

        short* base = sm + cur * BUFSH;
        half8v ahi[2], alo[2], bhi[NJ], blo[NJ];
#pragma unroll
        for (int i = 0; i < 2; ++i) {
            int ra = wm * 32 + i * 16 + lm;
            int offa = ra * 32 + (lk ^ ((ra >> 1) & 3)) * 8;
            ahi[i] = *(const half8v*)&base[offa];
            alo[i] = *(const half8v*)&base[4096 + offa];
        }
#pragma unroll
        for (int j = 0; j < NJ; ++j) {
            int rb = wn * (BN >> 1) + j * 16 + lm;
            int offb = rb * 32 + (lk ^ ((rb >> 1) & 3)) * 8;
            bhi[j] = *(const half8v*)&base[8192 + offb];
            blo[j] = *(const half8v*)&base[8192 + BN * 32 + offb];
        }
#pragma unroll
        for (int i = 0; i < 2; ++i)
#pragma unroll
            for (int j = 0; j < NJ; ++j) {
                acc[i][j]  = __builtin_amdgcn_mfma_f32_16x16x32_f16(ahi[i], bhi[j], acc[i][j], 0, 0, 0);
                acc2[i][j] = __builtin_amdgcn_mfma_f32_16x16x32_f16(ahi[i], blo[j], acc2[i][j], 0, 0, 0);
                acc2[i][j] = __builtin_amdgcn_mfma_f32_16x16x32_f16(alo[i], bhi[j], acc2[i][j], 0, 0, 0);
            }
        cur ^= 1;
    }

    const float ls = 1.0f / 4096.0f;

    if constexpr (FUSE) {
        // BN=128, NJ=4: col = n0 + wn*64 + j*16 + lm -> gate = j,
        // h = lm + 16*((n0>>6) + wn)
        const int h = lm + 16 * ((n0 >> 6) + wn);
#pragma unroll
        for (int i = 0; i < 2; ++i) {
#pragma unroll
            for (int r = 0; r < 4; ++r) {
                int brow = m0 + wm * 32 + i * 16 + lk * 4 + r;
                float gi = acc[i][0][r] + ls * acc2[i][0][r] + bb[0];
                float gf = acc[i][1][r] + ls * acc2[i][1][r] + bb[1];
                float gg = acc[i][2][r] + ls * acc2[i][2][r] + bb[2];
                float go = acc[i][3][r] + ls * acc2[i][3][r] + bb[3];
                size_t ch = ((size_t)brow << 9) + h;
                float c = sigm(gf) * Cst[ch] + sigm(gi) * tanhf(gg);
                float hn = sigm(go) * tanhf(c);
                Cst[ch] = c;
                short shi, slo; split2(hn, shi, slo);
                size_t xb = ((size_t)brow << 10) + 512 + h;
                Xh[xb] = shi; Xl[xb] = slo;
            }
        }
    } else {
        __syncthreads();                           // all tile reads complete (LDS reuse)
        // LDS-transpose epilogue -> coalesced float4 stores
        constexpr int SW = 16 * NJ + 4;
        float* tile = reinterpret_cast<float*>(sm) + wv * 16 * SW;
        constexpr int LPR = 4 * NJ;                // lanes per row (16B chunks)
        const int rl = lane / LPR, cc = lane % LPR;
#pragma unroll
        for (int i = 0; i < 2; ++i) {
#pragma unroll
            for (int j = 0; j < NJ; ++j)
#pragma unroll
                for (int r = 0; r < 4; ++r)
                    tile[(lk * 4 + r) * SW + j * 16 + lm] = acc[i][j][r] + ls * acc2[i][j][r] + bb[j];
            constexpr int RPS = 64 / LPR;          // rows per sweep
#pragma unroll
            for (int s = 0; s < 16 / RPS; ++s) {
                int row = s * RPS + rl;
                float4 v = *(float4*)&tile[row * SW + cc * 4];
                *(float4*)(out + (size_t)(m0 + wm * 32 + i * 16 + row) * N +
                           n0 + wn * (BN >> 1) + cc * 4) = v;
            }
        }
    }
}

// ---------------- attention + argmax + mask + gather into X_next ----------------
// 4 waves; wave wv owns t = 2*wv and 2*wv+1 (full 512-dot per wave).
__global__ __launch_bounds__(256) void k_attn(const float* __restrict__ W1E,
                                              const float* __restrict__ W2h,
                                              const float* __restrict__ vw,
                                              const float* __restrict__ vbp,
                                              const float* __restrict__ inps,
                                              short* __restrict__ Xhi,
                                              short* __restrict__ Xlo,
                                              int* __restrict__ mask,
                                              float* __restrict__ probs,
                                              float* __restrict__ ptrs,
                                              int step) {
    const int b = blockIdx.x;
    const int tid = threadIdx.x;
    const int lane = tid & 63;
    const int wv = tid >> 6;
    __shared__ float sU[Tn];
    __shared__ int sptr;

    const float4* w2p = (const float4*)(W2h + (size_t)b * Hn + lane * 8);
    float4 w2a = w2p[0], w2b = w2p[1];
    const float4* vp = (const float4*)(vw + lane * 8);
    float4 va = vp[0], vb4 = vp[1];
    float vbias = vbp[0];

#pragma unroll
    for (int q = 0; q < 2; ++q) {
        int t = wv * 2 + q;
        const float4* w1 = (const float4*)(W1E + ((size_t)b << 12) + t * Hn + lane * 8);
        float4 u0 = w1[0], u1 = w1[1];
        float p = va.x * tanhf(u0.x + w2a.x) + va.y * tanhf(u0.y + w2a.y)
                + va.z * tanhf(u0.z + w2a.z) + va.w * tanhf(u0.w + w2a.w)
                + vb4.x * tanhf(u1.x + w2b.x) + vb4.y * tanhf(u1.y + w2b.y)
                + vb4.z * tanhf(u1.z + w2b.z) + vb4.w * tanhf(u1.w + w2b.w);
#pragma unroll
        for (int off = 32; off; off >>= 1) p += __shfl_down(p, off, 64);
        if (lane == 0) sU[t] = p + vbias;
    }
    __syncthreads();

    if (tid == 0) {
        int mk = mask[b];
        float best = -1e30f;
        int ptr = 0;
#pragma unroll
        for (int t = 0; t < Tn; ++t) {
            probs[(size_t)b * 64 + step * 8 + t] = sU[t];
            if (!((mk >> t) & 1) && sU[t] > best) { best = sU[t]; ptr = t; }
        }
        mask[b] = mk | (1 << ptr);
        ptrs[(size_t)b * 8 + step] = (float)ptr;
        sptr = ptr;
    }
    __syncthreads();
    const float2* src = (const float2*)(inps + ((size_t)b << 12) + (size_t)sptr * Hn);
    float2 v = src[tid];
    short h0, l0, h1, l1;
    split2(v.x, h0, l0); split2(v.y, h1, l1);
    size_t xb = ((size_t)b << 10) + tid * 2;
    *(short2*)&Xhi[xb] = make_short2(h0, h1);
    *(short2*)&Xlo[xb] = make_short2(l0, l1);
}

// ---------------- launch ----------------
extern "C" void kernel_launch(void* const* d_in, const int* in_sizes, int n_in,
                              void* d_out, int out_size, void* d_ws, size_t ws_size,
                              hipStream_t stream) {
    const float* inps  = (const float*)d_in[0];
    const float* enc   = (const float*)d_in[1];
    const float* convw = (const float*)d_in[2];
    const float* convb = (const float*)d_in[3];
    const float* Wih   = (const float*)d_in[4];
    const float* Whh   = (const float*)d_in[5];
    const float* bih   = (const float*)d_in[6];
    const float* bhh   = (const float*)d_in[7];
    const float* W1    = (const float*)d_in[8];
    const float* b1    = (const float*)d_in[9];
    const float* W2    = (const float*)d_in[10];
    const float* b2    = (const float*)d_in[11];
    const float* vw    = (const float*)d_in[12];
    const float* vb    = (const float*)d_in[13];

    float* out   = (float*)d_out;
    float* probs = out;                       // [B, 8, 8]
    float* ptrs  = out + (size_t)Bn * 64;     // [B, 8] as float

    // Workspace map. ALIASING CONSTRAINTS (write-after-last-read order):
    //   encHi [64,96MB) aliased by Xhi1/Xlo1 (first write: step-0 FUSE)   -> after W1E gemm OK
    //   encLo [96,128MB) aliased by W2h (step 0), C/Xhi0/Xlo0 (k_init)    -> k_init MUST run after W1E gemm
    char* wsb = (char*)d_ws;
    float* W1E    = (float*)wsb;                          // [0,64MB) fp32 [B*T,512]
    short* encHi  = (short*)(wsb + (64ull << 20));        // dead after W1E gemm
    short* encLo  = (short*)(wsb + (96ull << 20));        // dead after W1E gemm
    short* Xhi1   = (short*)(wsb + (64ull << 20));        // 8MB fp16 [B,1024]
    short* Xlo1   = (short*)(wsb + (72ull << 20));        // 8MB
    float* W2h    = (float*)(wsb + (96ull << 20));        // 8MB fp32 [B,512]
    float* C      = (float*)(wsb + (104ull << 20));       // 8MB fp32 [B,512]
    short* Xhi0   = (short*)(wsb + (112ull << 20));       // 8MB
    short* Xlo0   = (short*)(wsb + (120ull << 20));       // 8MB
    short* WcatHi = (short*)(wsb + (128ull << 20));       // 4MB [2048,1024]
    short* WcatLo = (short*)(wsb + (132ull << 20));       // 4MB
    short* W1hi   = (short*)(wsb + (136ull << 20));
    short* W1lo   = (short*)(wsb + (136ull << 20) + (512u << 10));
    short* W2hi   = (short*)(wsb + (137ull << 20));
    short* W2lo   = (short*)(wsb + (137ull << 20) + (512u << 10));
    float* bcat   = (float*)(wsb + (138ull << 20));
    int*   mask   = (int*)(wsb + (138ull << 20) + (16u << 10));

    k_prep<<<(2048 * 1024) / 256, 256, 0, stream>>>(Wih, Whh, bih, bhh, WcatHi, WcatLo, bcat);
    k_split4<<<(Bn * Tn * Hn / 4) / 256, 256, 0, stream>>>(enc, encHi, encLo, Bn * Tn * Hn / 4);
    k_split4<<<(Hn * Hn / 4) / 256, 256, 0, stream>>>(W1, W1hi, W1lo, Hn * Hn / 4);
    k_split4<<<(Hn * Hn / 4) / 256, 256, 0, stream>>>(W2, W2hi, W2lo, Hn * Hn / 4);

    // W1E = enc @ W1^T + b1   [B*T, 512], K=512  (must complete before k_init clobbers encLo)
    gemm_t<4, false, 2><<<dim3(Hn / 128, (Bn * Tn) / 128), 512, 0, stream>>>(
        encHi, encLo, Hn, W1hi, W1lo, Hn, b1, W1E, nullptr, nullptr, nullptr, Hn, Hn);

    k_init<<<(Bn * Hn) / 256, 256, 0, stream>>>(enc, convw, convb, Xhi0, Xlo0, C, mask);

    for (int step = 0; step < Tn; ++step) {
        short* Xh_cur = (step & 1) ? Xhi1 : Xhi0;
        short* Xl_cur = (step & 1) ? Xlo1 : Xlo0;
        short* Xh_nxt = (step & 1) ? Xhi0 : Xhi1;
        short* Xl_nxt = (step & 1) ? Xlo0 : Xlo1;

        // gates GEMM + fused LSTM cell: reads X_cur, writes h into X_next, updates C.
        // Step 0: h == 0, so only the inp@Wih^T half is needed -> K=512 (Wcat cols 0:511),
        // bit-identical (MFMA adds exact zeros otherwise).
        gemm_t<4, true, 1><<<dim3(2048 / 128, Bn / 128), 512, 0, stream>>>(
            Xh_cur, Xl_cur, 1024, WcatHi, WcatLo, 1024, bcat, nullptr, C,
            Xh_nxt, Xl_nxt, 2048, (step == 0) ? 512 : 1024);
        // W2h = h @ W2^T + b2   [4096,512], K=512  (h = X_next[:,512:])
        gemm_t<2, false, 3><<<dim3(Hn / 64, Bn / 128), 512, 0, stream>>>(
            Xh_nxt + 512, Xl_nxt + 512, 1024, W2hi, W2lo, Hn, b2, W2h,
            nullptr, nullptr, nullptr, Hn, Hn);
        // attention, argmax, mask, gather next input into X_next[:,0:512]
        k_attn<<<Bn, 256, 0, stream>>>(W1E, W2h, vw, vb, inps, Xh_nxt, Xl_nxt, mask, probs, ptrs, step);
    }
}